// Round 5
// baseline (56.571 us; speedup 1.0000x reference)
//
#include <hip/hip_runtime.h>

// Problem constants (match reference)
#define LDIM 128
#define FDIM 64
#define NVALS 129      // counts range 0..128
#define NODE_MAX 1024  // id domain [0, 1024)
#define NPAIR (NVALS * NVALS)   // 16641 (a,b) pairs

typedef float f32x4 __attribute__((ext_vector_type(4)));

// ---------------------------------------------------------------------------
// Kernel 1 (prep): grid = 33 + B blocks, 256 threads.
//   blocks [0,33):    lookup table T[v][g] = relu(v*W1+b1)@W2 + b2, 4 v's/block
//   blocks [33,33+B): per-row counts via LDS histogram, packed as
//                     q = self*129 + cross (u16), src rows then dst rows.
// feat(pos) = T[self] + T[cross] = TS[q]; masked pos -> q=0 -> TS[0]=2*T[0],
// which equals the reference's encode of freq (0,0).
// ---------------------------------------------------------------------------
__global__ __launch_bounds__(256) void prep_kernel(
    const int* __restrict__ src, const int* __restrict__ dst,
    const float* __restrict__ W1, const float* __restrict__ b1,
    const float* __restrict__ W2, const float* __restrict__ b2,
    float* __restrict__ T, unsigned short* __restrict__ idx, int B)
{
    const int t = threadIdx.x;

    if (blockIdx.x < 33) {
        // ---- table part: v = 4*blk + (t>>6), g = t&63 ----
        const int vi = t >> 6, g = t & 63;
        const int v  = blockIdx.x * 4 + vi;
        __shared__ float h[4][FDIM];
        h[vi][g] = fmaxf((float)v * W1[g] + b1[g], 0.0f);
        __syncthreads();
        if (v < NVALS) {
            float acc = b2[g];
#pragma unroll
            for (int f = 0; f < FDIM; ++f)
                acc = fmaf(h[vi][f], W2[f * FDIM + g], acc);  // W2[f][g]
            T[v * FDIM + g] = acc;
        }
        return;
    }

    // ---- counts part ----
    const int row = blockIdx.x - 33;
    __shared__ int sID[LDIM], dID[LDIM];
    __shared__ int histS[NODE_MAX], histD[NODE_MAX];

    ((int4*)histS)[t] = make_int4(0, 0, 0, 0);
    ((int4*)histD)[t] = make_int4(0, 0, 0, 0);
    if (t < LDIM) sID[t] = src[(size_t)row * LDIM + t];
    else          dID[t - LDIM] = dst[(size_t)row * LDIM + (t - LDIM)];
    __syncthreads();

    if (t < LDIM) atomicAdd(&histS[sID[t]], 1);
    else          atomicAdd(&histD[dID[t - LDIM]], 1);
    __syncthreads();

    if (t < LDIM) {
        const int id = sID[t];
        int a = histS[id], c = histD[id];        // [self in src, cross in dst]
        if (id == 0) { a = 0; c = 0; }
        idx[(size_t)row * LDIM + t] = (unsigned short)(a * NVALS + c);
    } else {
        const int p = t - LDIM;
        const int id = dID[p];
        int a = histD[id], c = histS[id];        // [self in dst, cross in src]
        if (id == 0) { a = 0; c = 0; }
        idx[(size_t)(B + row) * LDIM + p] = (unsigned short)(a * NVALS + c);
    }
}

// ---------------------------------------------------------------------------
// Kernel 2 (pair-sum table): TS[a*129+b][g] = T[a][g] + T[b][g].
// grid = dim3(33, 129), 256 threads: b = bx*4 + (t>>6), a = by, g = t&63.
// 4.26 MB write, ~2 us. Hot region at runtime is tiny (a,b mostly <= 4).
// ---------------------------------------------------------------------------
__global__ __launch_bounds__(256) void ts_kernel(
    const float* __restrict__ T, float* __restrict__ TS)
{
    const int t = threadIdx.x;
    const int g = t & 63, vi = t >> 6;
    const int b = blockIdx.x * 4 + vi;
    const int a = blockIdx.y;
    if (b < NVALS)
        TS[((size_t)(a * NVALS + b)) * FDIM + g] = T[a * FDIM + g] + T[b * FDIM + g];
}

// ---------------------------------------------------------------------------
// Kernel 3 (stream): 2 VMEM per 16B — u16 q load (L1 broadcast, 16 lanes
// share), ONE f32x4 gather from TS (L1-hot), one coalesced store.
// No LDS, no barriers, no prologue.
// ---------------------------------------------------------------------------
__global__ __launch_bounds__(256) void stream_kernel(
    const unsigned short* __restrict__ idx, const float* __restrict__ TS,
    f32x4* __restrict__ out, int total4)
{
    const f32x4* __restrict__ TS4 = (const f32x4*)TS;   // TS4[q*16 + ch]
    const int tid    = blockIdx.x * 256 + threadIdx.x;
    const int stride = gridDim.x * 256;
#pragma unroll 8
    for (int c = tid; c < total4; c += stride) {
        const unsigned int q = idx[c >> 4];
        out[c] = TS4[q * 16u + (c & 15u)];
    }
}

// ---------------------------------------------------------------------------
// Fallback (ws too small): R1-style fused kernel (table via prep's 33 blocks).
// ---------------------------------------------------------------------------
__global__ __launch_bounds__(256) void encode_rows_kernel(
    const int* __restrict__ src, const int* __restrict__ dst,
    const float* __restrict__ T,
    float* __restrict__ out_src, float* __restrict__ out_dst)
{
    const int b = blockIdx.x;
    const int t = threadIdx.x;

    __shared__ int sID[LDIM], dID[LDIM];
    __shared__ int histS[NODE_MAX], histD[NODE_MAX];
    __shared__ int aS[LDIM], bS[LDIM], aD[LDIM], bD[LDIM];

    ((int4*)histS)[t] = make_int4(0, 0, 0, 0);
    ((int4*)histD)[t] = make_int4(0, 0, 0, 0);
    if (t < LDIM) sID[t] = src[(size_t)b * LDIM + t];
    else          dID[t - LDIM] = dst[(size_t)b * LDIM + (t - LDIM)];
    __syncthreads();

    if (t < LDIM) atomicAdd(&histS[sID[t]], 1);
    else          atomicAdd(&histD[dID[t - LDIM]], 1);
    __syncthreads();

    if (t < LDIM) {
        const int id = sID[t];
        int a = histS[id], c = histD[id];
        if (id == 0) { a = 0; c = 0; }
        aS[t] = a; bS[t] = c;
    } else {
        const int id = dID[t - LDIM];
        int a = histD[id], c = histS[id];
        if (id == 0) { a = 0; c = 0; }
        aD[t - LDIM] = a; bD[t - LDIM] = c;
    }
    __syncthreads();

    const f32x4* __restrict__ T4 = (const f32x4*)T;
    f32x4* __restrict__ o4s = (f32x4*)out_src;
    f32x4* __restrict__ o4d = (f32x4*)out_dst;
    const size_t rowBase = (size_t)b * (LDIM * FDIM / 4);

#pragma unroll
    for (int k = 0; k < 8; ++k) {
        const int c   = t + k * 256;
        const int pos = c >> 4;
        const int ch  = c & 15;
        o4s[rowBase + c] = T4[aS[pos] * 16 + ch] + T4[bS[pos] * 16 + ch];
        o4d[rowBase + c] = T4[aD[pos] * 16 + ch] + T4[bD[pos] * 16 + ch];
    }
}

extern "C" void kernel_launch(void* const* d_in, const int* in_sizes, int n_in,
                              void* d_out, int out_size, void* d_ws, size_t ws_size,
                              hipStream_t stream)
{
    const int*   src = (const int*)d_in[0];
    const int*   dst = (const int*)d_in[1];
    const float* W1  = (const float*)d_in[2];  // [1,F]
    const float* b1  = (const float*)d_in[3];  // [F]
    const float* W2  = (const float*)d_in[4];  // [F,F]
    const float* b2  = (const float*)d_in[5];  // [F]

    float* out = (float*)d_out;                // [src_feat | dst_feat]
    float* T   = (float*)d_ws;                 // 129*64 f32 = 33 KB

    const int B = in_sizes[0] / LDIM;          // 4096
    const size_t ts_off    = 33280;            // after T, 256B-aligned
    const size_t ts_bytes  = (size_t)NPAIR * FDIM * sizeof(float);   // 4,260,096
    const size_t idx_off   = ts_off + ts_bytes;                      // 4,293,376
    const size_t idx_bytes = (size_t)2 * B * LDIM * sizeof(unsigned short);

    if (ws_size >= idx_off + idx_bytes) {
        float*          TS  = (float*)((char*)d_ws + ts_off);
        unsigned short* idx = (unsigned short*)((char*)d_ws + idx_off);
        const int total4 = 2 * B * LDIM * (FDIM / 4);          // 16,777,216
        int nblk = total4 / (256 * 8); if (nblk < 1) nblk = 1;
        prep_kernel<<<33 + B, 256, 0, stream>>>(src, dst, W1, b1, W2, b2, T, idx, B);
        ts_kernel<<<dim3(33, NVALS), 256, 0, stream>>>(T, TS);
        stream_kernel<<<nblk, 256, 0, stream>>>(idx, TS, (f32x4*)out, total4);
    } else {
        // Fallback: build T (prep's first 33 blocks never touch idx), then fused.
        prep_kernel<<<33, 256, 0, stream>>>(src, dst, W1, b1, W2, b2, T,
                                            (unsigned short*)nullptr, B);
        const size_t half = (size_t)B * LDIM * FDIM;
        encode_rows_kernel<<<B, 256, 0, stream>>>(src, dst, T, out, out + half);
    }
}

// Round 6
// 54.004 us; speedup vs baseline: 1.0475x; 1.0475x over previous
//
#include <hip/hip_runtime.h>

// Problem constants (match reference)
#define LDIM 128
#define FDIM 64
#define NVALS 129      // counts range 0..128
#define NODE_MAX 1024  // id domain [0, 1024)

typedef float f32x4 __attribute__((ext_vector_type(4)));

// ---------------------------------------------------------------------------
// Kernel 1: lookup table T[v][g] = relu(v*W1+b1)@W2 + b2.  33 blocks, 4 v each.
// feat(pos) = T[self_cnt] + T[cross_cnt]; masked pos -> T[0]+T[0], which equals
// the reference's encode of freq (0,0).
// ---------------------------------------------------------------------------
__global__ __launch_bounds__(256) void build_table_kernel(
    const float* __restrict__ W1, const float* __restrict__ b1,
    const float* __restrict__ W2, const float* __restrict__ b2,
    float* __restrict__ T)
{
    const int t  = threadIdx.x;
    const int vi = t >> 6, g = t & 63;
    const int v  = blockIdx.x * 4 + vi;

    __shared__ float h[4][FDIM];
    h[vi][g] = fmaxf((float)v * W1[g] + b1[g], 0.0f);
    __syncthreads();

    if (v < NVALS) {
        float acc = b2[g];
#pragma unroll
        for (int f = 0; f < FDIM; ++f)
            acc = fmaf(h[vi][f], W2[f * FDIM + g], acc);  // W2[f][g]
        T[v * FDIM + g] = acc;
    }
}

// ---------------------------------------------------------------------------
// Kernel 2 (fused): one block per batch row, 256 threads.
//   Phase A: zero 2x4KB LDS histograms, stage src/dst ids.
//   Phase B: 256 LDS atomicAdds -> per-row histograms; counts = 2 LDS reads.
//            (order-independent -> deterministic; prologue ~<1us, overlaps
//            across the 8 resident blocks/CU)
//   Phase C: stream 2x128x64 f32 as PLAIN f32x4 stores (NT regressed in R3),
//            gathering T[a]+T[b] (hot T rows ~1.3KB, L1-resident).
// No separate prep dispatch, no idx round-trip (saves ~6us vs split R4).
// ---------------------------------------------------------------------------
__global__ __launch_bounds__(256) void encode_rows_kernel(
    const int* __restrict__ src, const int* __restrict__ dst,
    const float* __restrict__ T,
    float* __restrict__ out_src, float* __restrict__ out_dst)
{
    const int b = blockIdx.x;
    const int t = threadIdx.x;

    __shared__ int sID[LDIM], dID[LDIM];
    __shared__ int histS[NODE_MAX], histD[NODE_MAX];
    __shared__ int aS[LDIM], bS[LDIM], aD[LDIM], bD[LDIM];

    // Phase A
    ((int4*)histS)[t] = make_int4(0, 0, 0, 0);
    ((int4*)histD)[t] = make_int4(0, 0, 0, 0);
    if (t < LDIM) sID[t] = src[(size_t)b * LDIM + t];
    else          dID[t - LDIM] = dst[(size_t)b * LDIM + (t - LDIM)];
    __syncthreads();

    // Phase B
    if (t < LDIM) atomicAdd(&histS[sID[t]], 1);
    else          atomicAdd(&histD[dID[t - LDIM]], 1);
    __syncthreads();

    if (t < LDIM) {
        const int id = sID[t];
        int a = histS[id], c = histD[id];        // [self in src, cross in dst]
        if (id == 0) { a = 0; c = 0; }           // padding mask -> freq (0,0)
        aS[t] = a; bS[t] = c;
    } else {
        const int id = dID[t - LDIM];
        int a = histD[id], c = histS[id];        // [self in dst, cross in src]
        if (id == 0) { a = 0; c = 0; }
        aD[t - LDIM] = a; bD[t - LDIM] = c;
    }
    __syncthreads();

    // Phase C: 2048 float4 per side per row.
    const f32x4* __restrict__ T4 = (const f32x4*)T;        // T4[v*16 + ch]
    f32x4* __restrict__ o4s = (f32x4*)out_src;
    f32x4* __restrict__ o4d = (f32x4*)out_dst;
    const size_t rowBase = (size_t)b * (LDIM * FDIM / 4);

#pragma unroll
    for (int k = 0; k < 8; ++k) {
        const int c   = t + k * 256;     // 0..2047
        const int pos = c >> 4;
        const int ch  = c & 15;
        o4s[rowBase + c] = T4[aS[pos] * 16 + ch] + T4[bS[pos] * 16 + ch];
        o4d[rowBase + c] = T4[aD[pos] * 16 + ch] + T4[bD[pos] * 16 + ch];
    }
}

extern "C" void kernel_launch(void* const* d_in, const int* in_sizes, int n_in,
                              void* d_out, int out_size, void* d_ws, size_t ws_size,
                              hipStream_t stream)
{
    const int*   src = (const int*)d_in[0];    // int64 in ref -> int32 from harness
    const int*   dst = (const int*)d_in[1];
    const float* W1  = (const float*)d_in[2];  // [1,F]
    const float* b1  = (const float*)d_in[3];  // [F]
    const float* W2  = (const float*)d_in[4];  // [F,F]
    const float* b2  = (const float*)d_in[5];  // [F]

    float* out = (float*)d_out;                // [src_feat | dst_feat]
    float* T   = (float*)d_ws;                 // 129*64 f32 = 33 KB

    const int B = in_sizes[0] / LDIM;          // 4096
    const size_t half = (size_t)B * LDIM * FDIM;

    build_table_kernel<<<33, 256, 0, stream>>>(W1, b1, W2, b2, T);
    encode_rows_kernel<<<B, 256, 0, stream>>>(src, dst, T, out, out + half);
}